// Round 1
// baseline (368.931 us; speedup 1.0000x reference)
//
#include <hip/hip_runtime.h>
#include <math.h>

#define N_OBS   2048
#define DIM_IN  64
#define K_HID   1024

// ---------------------------------------------------------------------------
// Kernel 0: transpose w (K,D) -> wt (D,K) so the expansion kernel can read
// w[.,d] rows contiguously.
// ---------------------------------------------------------------------------
__global__ __launch_bounds__(256) void rff_transpose_w(
    const float* __restrict__ w, float* __restrict__ wt) {
    int t = blockIdx.x * 256 + threadIdx.x;          // 0 .. 65535
    int l = t >> 6;                                   // row of w (K)
    int d = t & 63;                                   // col of w (D)
    wt[d * K_HID + l] = w[t];
}

// ---------------------------------------------------------------------------
// Kernel 1: s[n,k] = -sqrt(2/K) * sin( dot(x[n,:], w[k,:]) + b[k] )
// Tile: 16 n-rows x 64 k-cols per block, 256 threads.
// ---------------------------------------------------------------------------
__global__ __launch_bounds__(256) void rff_compute_s(
    const float* __restrict__ x, const float* __restrict__ w,
    const float* __restrict__ b, float* __restrict__ s) {
    __shared__ float xs[16][64];        // broadcast reads, no pad needed
    __shared__ float wtile[64][68];     // pad 68 keeps float4 stores aligned

    const int t  = threadIdx.x;
    const int k0 = blockIdx.x * 64;
    const int n0 = blockIdx.y * 16;

    // load x tile (16x64 floats = 256 float4, one per thread)
    {
        int r = t >> 4, c = (t & 15) * 4;
        *(float4*)&xs[r][c] = *(const float4*)(x + (n0 + r) * DIM_IN + c);
    }
    // load w tile (64x64 floats = 1024 float4, four per thread)
#pragma unroll
    for (int i = 0; i < 4; ++i) {
        int r = (t >> 4) + 16 * i, c = (t & 15) * 4;
        *(float4*)&wtile[r][c] = *(const float4*)(w + (k0 + r) * DIM_IN + c);
    }
    __syncthreads();

    const int k  = t & 63;
    const int nb = t >> 6;              // 0..3 -> handles n = nb*4 .. nb*4+3
    float z[4];
    const float bk = b[k0 + k];
#pragma unroll
    for (int i = 0; i < 4; ++i) z[i] = bk;

#pragma unroll
    for (int d = 0; d < 64; ++d) {
        const float wv = wtile[k][d];
#pragma unroll
        for (int i = 0; i < 4; ++i) z[i] += xs[nb * 4 + i][d] * wv;
    }

    const float scale = 0.04419417382415922f;  // sqrt(2/1024)
#pragma unroll
    for (int i = 0; i < 4; ++i) {
        s[(size_t)(n0 + nb * 4 + i) * K_HID + k0 + k] = -scale * sinf(z[i]);
    }
}

// ---------------------------------------------------------------------------
// Kernel 2: M = (1/n) * s^T s   (K x K, inner dim n=2048)
// 64x64 output tile per block, 4x4 per thread, k-chunks of 32.
// ---------------------------------------------------------------------------
__global__ __launch_bounds__(256) void rff_compute_M(
    const float* __restrict__ s, float* __restrict__ M) {
    const int PAD = 68;                 // multiple of 4 -> aligned float4 LDS ops
    __shared__ float sk[32 * PAD];
    __shared__ float sl[32 * PAD];

    const int t  = threadIdx.x;
    const int tx = t & 15;              // l micro-index
    const int ty = t >> 4;              // k micro-index
    const int l0 = blockIdx.x * 64;
    const int k0 = blockIdx.y * 64;

    float acc[4][4];
#pragma unroll
    for (int i = 0; i < 4; ++i)
#pragma unroll
        for (int j = 0; j < 4; ++j) acc[i][j] = 0.0f;

    for (int n0 = 0; n0 < N_OBS; n0 += 32) {
        // stage 32x64 chunks of the k-columns and l-columns of s
#pragma unroll
        for (int p = 0; p < 2; ++p) {
            int r = (t >> 4) + 16 * p;
            int c = (t & 15) * 4;
            *(float4*)&sk[r * PAD + c] =
                *(const float4*)(s + (size_t)(n0 + r) * K_HID + k0 + c);
            *(float4*)&sl[r * PAD + c] =
                *(const float4*)(s + (size_t)(n0 + r) * K_HID + l0 + c);
        }
        __syncthreads();

#pragma unroll
        for (int nn = 0; nn < 32; ++nn) {
            float4 a = *(const float4*)&sk[nn * PAD + ty * 4];
            float4 bv = *(const float4*)&sl[nn * PAD + tx * 4];
            float av[4] = {a.x, a.y, a.z, a.w};
            float bw[4] = {bv.x, bv.y, bv.z, bv.w};
#pragma unroll
            for (int i = 0; i < 4; ++i)
#pragma unroll
                for (int j = 0; j < 4; ++j) acc[i][j] += av[i] * bw[j];
        }
        __syncthreads();
    }

    const float inv_n = 1.0f / (float)N_OBS;
#pragma unroll
    for (int i = 0; i < 4; ++i) {
        float4 o = make_float4(acc[i][0] * inv_n, acc[i][1] * inv_n,
                               acc[i][2] * inv_n, acc[i][3] * inv_n);
        *(float4*)(M + (size_t)(k0 + ty * 4 + i) * K_HID + l0 + tx * 4) = o;
    }
}

// ---------------------------------------------------------------------------
// Kernel 3: A[d,k,l] = M[k,l] * wt[d,k] * wt[d,l]
// One block per (d,k); 256 threads each write one float4 of l.
// d varies fastest in the grid so 64 consecutive blocks reuse one M row.
// ---------------------------------------------------------------------------
__global__ __launch_bounds__(256) void rff_expand_A(
    const float* __restrict__ M, const float* __restrict__ wt,
    float* __restrict__ out) {
    const int d = blockIdx.x;           // 0..63
    const int k = blockIdx.y;           // 0..1023
    const int t = threadIdx.x;

    const float wk = wt[d * K_HID + k];
    const float4 m  = *(const float4*)(M + (size_t)k * K_HID + t * 4);
    const float4 wl = *(const float4*)(wt + (size_t)d * K_HID + t * 4);

    float4 o = make_float4(m.x * wk * wl.x, m.y * wk * wl.y,
                           m.z * wk * wl.z, m.w * wk * wl.w);
    *(float4*)(out + ((size_t)(d * K_HID + k)) * K_HID + t * 4) = o;
}

// ---------------------------------------------------------------------------
extern "C" void kernel_launch(void* const* d_in, const int* in_sizes, int n_in,
                              void* d_out, int out_size, void* d_ws, size_t ws_size,
                              hipStream_t stream) {
    const float* x = (const float*)d_in[0];   // (2048, 64)
    const float* w = (const float*)d_in[1];   // (1024, 64)
    const float* b = (const float*)d_in[2];   // (1024,)
    float* out = (float*)d_out;               // (64, 1024, 1024)

    float* ws = (float*)d_ws;
    float* s_buf  = ws;                               // 2048*1024 floats (8 MB)
    float* M_buf  = ws + (size_t)N_OBS * K_HID;       // 1024*1024 floats (4 MB)
    float* wt_buf = M_buf + (size_t)K_HID * K_HID;    // 64*1024 floats (256 KB)

    rff_transpose_w<<<dim3((K_HID * DIM_IN) / 256), 256, 0, stream>>>(w, wt_buf);
    rff_compute_s<<<dim3(K_HID / 64, N_OBS / 16), 256, 0, stream>>>(x, w, b, s_buf);
    rff_compute_M<<<dim3(K_HID / 64, K_HID / 64), 256, 0, stream>>>(s_buf, M_buf);
    rff_expand_A<<<dim3(DIM_IN, K_HID), 256, 0, stream>>>(M_buf, wt_buf, out);
}

// Round 2
// 299.646 us; speedup vs baseline: 1.2312x; 1.2312x over previous
//
#include <hip/hip_runtime.h>
#include <math.h>

#define N_OBS   2048
#define DIM_IN  64
#define K_HID   1024

typedef unsigned short ushort_t;
typedef __attribute__((ext_vector_type(8))) short bf16x8;
typedef __attribute__((ext_vector_type(4))) float f32x4;

__device__ __forceinline__ ushort_t f2bf(float f) {
    unsigned int u = __float_as_uint(f);
    u += 0x7FFF + ((u >> 16) & 1);          // round-to-nearest-even
    return (ushort_t)(u >> 16);
}

// ---------------------------------------------------------------------------
// Kernel 0: transpose w (K,D) -> wt (D,K) fp32 for the expand kernel.
// ---------------------------------------------------------------------------
__global__ __launch_bounds__(256) void rff_transpose_w(
    const float* __restrict__ w, float* __restrict__ wt) {
    int t = blockIdx.x * 256 + threadIdx.x;  // 0..65535
    int l = t >> 6;                          // k index
    int d = t & 63;                          // d index
    wt[d * K_HID + l] = w[t];
}

// ---------------------------------------------------------------------------
// Kernel 1: sT[k,n] = bf16( -sqrt(2/K) * sin( dot(x[n,:], w[k,:]) + b[k] ) )
// Block tile: 16 n x 64 k. wT LDS pad=65 -> conflict-free per-lane reads.
// ---------------------------------------------------------------------------
__global__ __launch_bounds__(256) void rff_compute_s(
    const float* __restrict__ x, const float* __restrict__ w,
    const float* __restrict__ b, ushort_t* __restrict__ sT) {
    __shared__ float xs[16][64];
    __shared__ float wT[64][65];             // [d][k], pad 65: bank = (d+k)%32

    const int t  = threadIdx.x;
    const int k0 = blockIdx.x * 64;
    const int n0 = blockIdx.y * 16;

    {   // x tile: 256 float4
        int r = t >> 4, c = (t & 15) * 4;
        *(float4*)&xs[r][c] = *(const float4*)(x + (n0 + r) * DIM_IN + c);
    }
#pragma unroll
    for (int i = 0; i < 4; ++i) {            // w tile, transposed into LDS
        int r = (t >> 4) + 16 * i, c = (t & 15) * 4;
        float4 v = *(const float4*)(w + (k0 + r) * DIM_IN + c);
        wT[c + 0][r] = v.x; wT[c + 1][r] = v.y;
        wT[c + 2][r] = v.z; wT[c + 3][r] = v.w;
    }
    __syncthreads();

    const int k  = t & 63;                   // lane = k -> conflict-free wT reads
    const int nb = t >> 6;                   // wave-uniform -> xs reads broadcast
    const float bk = b[k0 + k];
    float z[4];
#pragma unroll
    for (int i = 0; i < 4; ++i) z[i] = bk;

    for (int d4 = 0; d4 < 64; d4 += 4) {
        float xv[4][4];
#pragma unroll
        for (int i = 0; i < 4; ++i)
            *(float4*)xv[i] = *(const float4*)&xs[nb * 4 + i][d4];
#pragma unroll
        for (int j = 0; j < 4; ++j) {
            const float wv = wT[d4 + j][k];
#pragma unroll
            for (int i = 0; i < 4; ++i) z[i] += xv[i][j] * wv;
        }
    }

    const float scale = 0.04419417382415922f;  // sqrt(2/1024)
    ushort4 ov;
    ov.x = f2bf(-scale * __sinf(z[0]));
    ov.y = f2bf(-scale * __sinf(z[1]));
    ov.z = f2bf(-scale * __sinf(z[2]));
    ov.w = f2bf(-scale * __sinf(z[3]));
    *(ushort4*)(sT + (size_t)(k0 + k) * N_OBS + n0 + nb * 4) = ov;
}

// ---------------------------------------------------------------------------
// Kernel 2: M = (1/n) * s^T s via bf16 MFMA, fp32 accumulate.
// 64x64 tile/block (grid 16x16 = 256 blocks), 4 waves each computing a 32x32
// quadrant as 2x2 of mfma_f32_16x16x32_bf16. Both operands read row-major
// from sT (K x n) -> contiguous-K "B^T input" layout (m92/m97 structure).
// Verified layouts: A[m=lane&15][k=(lane>>4)*8+j]; B[k][nn=lane&15];
// C/D col=lane&15, row=(lane>>4)*4+reg.
// ---------------------------------------------------------------------------
__global__ __launch_bounds__(256) void rff_gram_mfma(
    const ushort_t* __restrict__ sT, float* __restrict__ M) {
    __shared__ ushort_t ldsA[64 * 64];       // k-rows tile, 64 x 64 bf16
    __shared__ ushort_t ldsB[64 * 64];       // l-rows tile

    const int t    = threadIdx.x;
    const int lane = t & 63;
    const int wv   = t >> 6;
    const int wr   = wv >> 1, wc = wv & 1;
    const int k0   = blockIdx.y * 64, l0 = blockIdx.x * 64;

    f32x4 acc[2][2];
#pragma unroll
    for (int a = 0; a < 2; ++a)
#pragma unroll
        for (int bb = 0; bb < 2; ++bb)
            acc[a][bb] = (f32x4){0.f, 0.f, 0.f, 0.f};

    const int srow = t >> 3;                 // 0..31
    const int scol = (t & 7) * 8;            // bf16 col offset (16B chunks)

    for (int n0 = 0; n0 < N_OBS; n0 += 64) {
        bf16x8 ra[2], rb[2];
#pragma unroll
        for (int i = 0; i < 2; ++i) {        // issue global loads before barrier
            ra[i] = *(const bf16x8*)(sT + (size_t)(k0 + i * 32 + srow) * N_OBS + n0 + scol);
            rb[i] = *(const bf16x8*)(sT + (size_t)(l0 + i * 32 + srow) * N_OBS + n0 + scol);
        }
        __syncthreads();                     // prev-chunk readers done
#pragma unroll
        for (int i = 0; i < 2; ++i) {        // flat offset == row*64+col mapping
            *(bf16x8*)(ldsA + i * 2048 + t * 8) = ra[i];
            *(bf16x8*)(ldsB + i * 2048 + t * 8) = rb[i];
        }
        __syncthreads();                     // tiles visible

#pragma unroll
        for (int ks = 0; ks < 2; ++ks) {     // two K=32 steps per 64-chunk
            bf16x8 af[2], bfr[2];
#pragma unroll
            for (int a = 0; a < 2; ++a) {
                af[a]  = *(const bf16x8*)(ldsA + (wr * 32 + a * 16 + (lane & 15)) * 64
                                          + ks * 32 + (lane >> 4) * 8);
                bfr[a] = *(const bf16x8*)(ldsB + (wc * 32 + a * 16 + (lane & 15)) * 64
                                          + ks * 32 + (lane >> 4) * 8);
            }
#pragma unroll
            for (int a = 0; a < 2; ++a)
#pragma unroll
                for (int bb = 0; bb < 2; ++bb)
                    acc[a][bb] = __builtin_amdgcn_mfma_f32_16x16x32_bf16(
                        af[a], bfr[bb], acc[a][bb], 0, 0, 0);
        }
    }

    const float inv_n = 1.0f / (float)N_OBS;
    const int col = lane & 15;
    const int rq  = (lane >> 4) * 4;
#pragma unroll
    for (int a = 0; a < 2; ++a)
#pragma unroll
        for (int bb = 0; bb < 2; ++bb)
#pragma unroll
            for (int r = 0; r < 4; ++r) {
                const int row = k0 + wr * 32 + a * 16 + rq + r;
                const int cl  = l0 + wc * 32 + bb * 16 + col;
                M[(size_t)row * K_HID + cl] = acc[a][bb][r] * inv_n;
            }
}

// ---------------------------------------------------------------------------
// Kernel 3: A[d,k,l] = M[k,l] * wt[d,k] * wt[d,l]
// Block = (k-group of 4, d); grid (256, 64), k fastest so each d-sweep
// streams M sequentially through L2. Pure write-BW bound.
// ---------------------------------------------------------------------------
__global__ __launch_bounds__(256) void rff_expand_A(
    const float* __restrict__ M, const float* __restrict__ wt,
    float* __restrict__ out) {
    const int kg = blockIdx.x;               // 0..255
    const int d  = blockIdx.y;               // 0..63
    const int t  = threadIdx.x;

    const float4 wl = *(const float4*)(wt + d * K_HID + t * 4);
    const int k0 = kg * 4;
#pragma unroll
    for (int i = 0; i < 4; ++i) {
        const int k = k0 + i;
        const float wk = wt[d * K_HID + k];  // block-uniform -> scalar load
        const float4 mv = *(const float4*)(M + (size_t)k * K_HID + t * 4);
        float4 o;
        o.x = mv.x * wk * wl.x;
        o.y = mv.y * wk * wl.y;
        o.z = mv.z * wk * wl.z;
        o.w = mv.w * wk * wl.w;
        *(float4*)(out + ((size_t)(d * K_HID + k)) * K_HID + t * 4) = o;
    }
}

// ---------------------------------------------------------------------------
extern "C" void kernel_launch(void* const* d_in, const int* in_sizes, int n_in,
                              void* d_out, int out_size, void* d_ws, size_t ws_size,
                              hipStream_t stream) {
    const float* x = (const float*)d_in[0];  // (2048, 64)
    const float* w = (const float*)d_in[1];  // (1024, 64)
    const float* b = (const float*)d_in[2];  // (1024,)
    float* out = (float*)d_out;              // (64, 1024, 1024)

    char* ws = (char*)d_ws;
    ushort_t* sT_buf = (ushort_t*)ws;                          // 4 MB bf16 (1024 x 2048)
    float*    M_buf  = (float*)(ws + (size_t)4 * 1024 * 1024); // 4 MB fp32 (1024 x 1024)
    float*    wt_buf = (float*)(ws + (size_t)8 * 1024 * 1024); // 256 KB fp32 (64 x 1024)

    rff_transpose_w<<<dim3((K_HID * DIM_IN) / 256), 256, 0, stream>>>(w, wt_buf);
    rff_compute_s<<<dim3(K_HID / 64, N_OBS / 16), 256, 0, stream>>>(x, w, b, sT_buf);
    rff_gram_mfma<<<dim3(K_HID / 64, K_HID / 64), 256, 0, stream>>>(sT_buf, M_buf);
    rff_expand_A<<<dim3(K_HID / 4, DIM_IN), 256, 0, stream>>>(M_buf, wt_buf, out);
}